// Round 4
// baseline (796.869 us; speedup 1.0000x reference)
//
#include <hip/hip_runtime.h>
#include <hip/hip_bf16.h>
#include <cstdint>

// Problem: B*H=64, N=1024 (32x32 grid), D=256. f32 in/out; bf16 internally.
#define BH     64
#define NTOK   1024
#define DDIM   256
#define QT     64             // q rows per block (16 per wave)
#define KTILE  32             // k tokens per iteration
#define NITER  (NTOK / KTILE) // 32
#define KPITCH 264            // ushort pitch for K tile rows (256 + 8 pad)
#define VPITCH 40             // ushort pitch for VT rows (32 + 8 pad)
#define PPITCH 40             // ushort pitch for P rows (32 + 8 pad)

typedef __bf16 bf16x8 __attribute__((ext_vector_type(8)));
typedef float  f32x4  __attribute__((ext_vector_type(4)));

__device__ __forceinline__ unsigned short f2bf(float f) {
    __bf16 b = (__bf16)f;                       // RTNE
    return __builtin_bit_cast(unsigned short, b);
}
__device__ __forceinline__ float bf2f(unsigned short u) {
    return __builtin_bit_cast(float, ((unsigned int)u) << 16);
}
__device__ __forceinline__ unsigned int pack2(float lo, float hi) {
    return (unsigned int)f2bf(lo) | ((unsigned int)f2bf(hi) << 16);
}

// inv[j] = 10000^(-j/64) = exp2(-j * log2(10000)/64),  j in [0,64)
#define ANG_C    (13.287712379549449f / 64.0f)
// softmax: exp(s/16) = exp2(s * log2(e)/16); no max subtraction (scores bounded,
// softmax scale-invariant; exponents stay in f32 range)
#define SM_SCALE (1.4426950408889634f / 16.0f)

// ---------------------------------------------------------------------------
// Kernel 1: 2D RoPE on K (f32) -> KR (bf16, same [bh][t][d] layout).
__global__ __launch_bounds__(256) void rope_k(const float* __restrict__ K,
                                              unsigned short* __restrict__ KR) {
    int gid = blockIdx.x * 256 + threadIdx.x;   // chunk id over [bh][t][32 chunks]
    int chunk = gid & 31;
    int t = (gid >> 5) & (NTOK - 1);
    float x = (float)(t & 31), y = (float)(t >> 5);
    const float4 a = *(const float4*)(K + (size_t)gid * 8);
    const float4 b = *(const float4*)(K + (size_t)gid * 8 + 4);
    float f[8] = {a.x, a.y, a.z, a.w, b.x, b.y, b.z, b.w};
    unsigned int o[4];
#pragma unroll
    for (int p = 0; p < 4; ++p) {
        int j = chunk * 4 + p;                  // pair index in [0,128)
        float pos = (j < 64) ? x : y;
        float inv = __builtin_exp2f(-(float)(j & 63) * ANG_C);
        float s, c;
        __sincosf(pos * inv, &s, &c);
        float x0 = f[2 * p], x1 = f[2 * p + 1];
        o[p] = pack2(x0 * c - x1 * s, x0 * s + x1 * c);
    }
    uint4 ov; ov.x = o[0]; ov.y = o[1]; ov.z = o[2]; ov.w = o[3];
    *(uint4*)(KR + (size_t)gid * 8) = ov;
}

// ---------------------------------------------------------------------------
// Kernel 2: V (f32, [bh][t][d]) -> VT (bf16, [bh][d][t]) via LDS tile.
__global__ __launch_bounds__(256) void transpose_v(const float* __restrict__ V,
                                                   unsigned short* __restrict__ VT) {
    __shared__ unsigned short tile[64 * 264];
    int tid = threadIdx.x;
    int bh = blockIdx.x >> 4;
    int tbase = (blockIdx.x & 15) * 64;
    const float* src = V + ((size_t)bh * NTOK + tbase) * DDIM;
#pragma unroll
    for (int i = 0; i < 8; ++i) {
        int flat = i * 2048 + tid * 8;
        int tl = flat >> 8, col = flat & 255;
        const float4 a = *(const float4*)(src + (size_t)tl * DDIM + col);
        const float4 b = *(const float4*)(src + (size_t)tl * DDIM + col + 4);
        uint4 ov;
        ov.x = pack2(a.x, a.y); ov.y = pack2(a.z, a.w);
        ov.z = pack2(b.x, b.y); ov.w = pack2(b.z, b.w);
        *(uint4*)(tile + tl * 264 + col) = ov;
    }
    __syncthreads();
    unsigned short* dst = VT + (size_t)bh * ((size_t)DDIM * NTOK) + tbase;
#pragma unroll
    for (int i = 0; i < 8; ++i) {
        int task = i * 256 + tid;
        int d = task >> 3, tq = task & 7;       // 8 consecutive tids -> one d row
        unsigned int o[4];
#pragma unroll
        for (int k = 0; k < 4; ++k) {
            unsigned short lo = tile[(tq * 8 + 2 * k    ) * 264 + d];
            unsigned short hi = tile[(tq * 8 + 2 * k + 1) * 264 + d];
            o[k] = (unsigned int)lo | ((unsigned int)hi << 16);
        }
        uint4 ov; ov.x = o[0]; ov.y = o[1]; ov.z = o[2]; ov.w = o[3];
        *(uint4*)(dst + (size_t)d * NTOK + tq * 8) = ov;
    }
}

// ---------------------------------------------------------------------------
// Kernel 3: flash attention, no-max softmax. Block = 256 thr (4 waves),
// 64 q rows (16/wave), 32 k-tiles of 32 tokens. Grid 1024, XCD-swizzled so all
// 16 q-blocks of one bh share one XCD's L2 (q varies fastest in dispatch order).
__global__ __launch_bounds__(256, 3) void flash_attn(
        const float* __restrict__ Q,
        const unsigned short* __restrict__ KR,
        const unsigned short* __restrict__ VTg,
        float* __restrict__ Out) {
    __shared__ unsigned short KTl[KTILE * KPITCH];   // 16896 B (>= 16x260 f32 stage)
    __shared__ unsigned short VTl[DDIM * VPITCH];    // 20480 B (>= 16x260 f32 stage)
    __shared__ unsigned short PB[4 * 16 * PPITCH];   //  5120 B (per-wave P)

    const int tid = threadIdx.x;
    const int wave = tid >> 6, lane = tid & 63;
    const int g = lane >> 4, l15 = lane & 15;
    // XCD swizzle: XCD = blockIdx%8. bh = (blk&7)*8 + (blk>>7); q = (blk>>3)&15.
    // All 16 blocks of a bh have blk%8 const -> same XCD; q fastest in dispatch.
    const int bh = (blockIdx.x & 7) * 8 + (blockIdx.x >> 7);
    const int qbase = ((blockIdx.x >> 3) & 15) * QT;

    // ---- Q fragments (A-operand: m=l15, k=g*8+j within 32-chunk kk), RoPE'd
    bf16x8 qfrag[8];
    {
        const int qtok = qbase + wave * 16 + l15;
        const float x = (float)(qtok & 31), y = (float)(qtok >> 5);
        const float* qrow = Q + ((size_t)bh * NTOK + qtok) * DDIM;
#pragma unroll
        for (int kk = 0; kk < 8; ++kk) {
            const float4 a = *(const float4*)(qrow + kk * 32 + g * 8);
            const float4 b = *(const float4*)(qrow + kk * 32 + g * 8 + 4);
            float f[8] = {a.x, a.y, a.z, a.w, b.x, b.y, b.z, b.w};
            unsigned int po[4];
#pragma unroll
            for (int p = 0; p < 4; ++p) {
                int j = kk * 16 + g * 4 + p;    // rotary pair index
                float pos = (j < 64) ? x : y;
                float inv = __builtin_exp2f(-(float)(j & 63) * ANG_C);
                float s, c;
                __sincosf(pos * inv, &s, &c);
                float x0 = f[2 * p], x1 = f[2 * p + 1];
                po[p] = pack2(x0 * c - x1 * s, x0 * s + x1 * c);
            }
            uint4 pk; pk.x = po[0]; pk.y = po[1]; pk.z = po[2]; pk.w = po[3];
            qfrag[kk] = __builtin_bit_cast(bf16x8, pk);
        }
    }

    f32x4 o[16];
    const f32x4 zero4 = {0.f, 0.f, 0.f, 0.f};
#pragma unroll
    for (int nt = 0; nt < 16; ++nt) o[nt] = zero4;
    float lsum[4] = {0.f, 0.f, 0.f, 0.f};       // per-lane partial row sums

    const unsigned short* krB = KR + (size_t)bh * ((size_t)NTOK * DDIM);
    const unsigned short* vtB = VTg + (size_t)bh * ((size_t)DDIM * NTOK);

    // register prefetch of tile 0
    uint4 kpre[4], vpre[4];
#pragma unroll
    for (int i = 0; i < 4; ++i) {
        int flat = i * 2048 + tid * 8;
        kpre[i] = *(const uint4*)(krB + (size_t)(flat >> 8) * DDIM + (flat & 255));
        vpre[i] = *(const uint4*)(vtB + (size_t)(flat >> 5) * NTOK + (flat & 31));
    }

    for (int it = 0; it < NITER; ++it) {
        __syncthreads();                        // prior iter's LDS reads done
#pragma unroll
        for (int i = 0; i < 4; ++i) {
            int flat = i * 2048 + tid * 8;
            *(uint4*)(KTl + (flat >> 8) * KPITCH + (flat & 255)) = kpre[i];
            *(uint4*)(VTl + (flat >> 5) * VPITCH + (flat & 31)) = vpre[i];
        }
        __syncthreads();                        // staging visible
        if (it + 1 < NITER) {                   // prefetch next tile into regs
            int kb = (it + 1) * KTILE;
#pragma unroll
            for (int i = 0; i < 4; ++i) {
                int flat = i * 2048 + tid * 8;
                kpre[i] = *(const uint4*)(krB + (size_t)(kb + (flat >> 8)) * DDIM + (flat & 255));
                vpre[i] = *(const uint4*)(vtB + (size_t)(flat >> 5) * NTOK + kb + (flat & 31));
            }
        }

        // ---- S = Q_rope · K_rope^T  (raw; 1/16 scale folded into exp2)
        f32x4 sc[2];
        sc[0] = zero4; sc[1] = zero4;
#pragma unroll
        for (int kk = 0; kk < 8; ++kk) {
#pragma unroll
            for (int c = 0; c < 2; ++c) {
                bf16x8 bf = *(const bf16x8*)(KTl + (c * 16 + l15) * KPITCH + kk * 32 + g * 8);
                sc[c] = __builtin_amdgcn_mfma_f32_16x16x32_bf16(qfrag[kk], bf, sc[c], 0, 0, 0);
            }
        }

        // ---- P = exp2(S*SM_SCALE) -> per-wave LDS (A-layout rows); partial sums
#pragma unroll
        for (int r = 0; r < 4; ++r) {
#pragma unroll
            for (int c = 0; c < 2; ++c) {
                float p = __builtin_exp2f(sc[c][r] * SM_SCALE);
                unsigned short pb = f2bf(p);
                PB[wave * (16 * PPITCH) + (4 * g + r) * PPITCH + c * 16 + l15] = pb;
                lsum[r] += bf2f(pb);            // denominator uses rounded P
            }
        }

        // ---- O += P · V  (A = P from LDS A-layout; B = VT rows, contiguous)
        // Same-wave LDS RAW: DS ops are program-ordered within a wave.
        bf16x8 af = *(const bf16x8*)(PB + wave * (16 * PPITCH) + l15 * PPITCH + g * 8);
#pragma unroll
        for (int nt = 0; nt < 16; ++nt) {
            bf16x8 bf = *(const bf16x8*)(VTl + (nt * 16 + l15) * VPITCH + g * 8);
            o[nt] = __builtin_amdgcn_mfma_f32_16x16x32_bf16(af, bf, o[nt], 0, 0, 0);
        }
    }

    // ---- final row-sum reduction (once) and reciprocal
    float rl[4];
#pragma unroll
    for (int r = 0; r < 4; ++r) {
        float s = lsum[r];
        s += __shfl_xor(s, 1);
        s += __shfl_xor(s, 2);
        s += __shfl_xor(s, 4);
        s += __shfl_xor(s, 8);
        rl[r] = 1.0f / s;
    }

    // ---- epilogue: stage scaled O in LDS (f32, pitch 260), write coalesced
    // float4 rows. Two rounds: waves {0,1} then {2,3}; wave0/2 use KTl region,
    // wave1/3 use VTl region (each >= 16*260*4 B).
    float* stage = (wave & 1) ? (float*)VTl : (float*)KTl;
#pragma unroll
    for (int round = 0; round < 2; ++round) {
        __syncthreads();                        // protect LDS reuse across waves
        if ((wave >> 1) == round) {
#pragma unroll
            for (int nt = 0; nt < 16; ++nt)
#pragma unroll
                for (int r = 0; r < 4; ++r)
                    stage[(4 * g + r) * 260 + nt * 16 + l15] = o[nt][r] * rl[r];
            // same-wave RAW through LDS: program order suffices
#pragma unroll
            for (int u = 0; u < 16; ++u) {
                float4 val = *(const float4*)(stage + u * 260 + lane * 4);
                *(float4*)(Out + ((size_t)bh * NTOK + qbase + wave * 16 + u) * DDIM + lane * 4) = val;
            }
        }
    }
}

// ---------------------------------------------------------------------------
extern "C" void kernel_launch(void* const* d_in, const int* in_sizes, int n_in,
                              void* d_out, int out_size, void* d_ws, size_t ws_size,
                              hipStream_t stream) {
    const float* Q = (const float*)d_in[0];
    const float* K = (const float*)d_in[1];
    const float* V = (const float*)d_in[2];
    unsigned short* KR = (unsigned short*)d_ws;                       // 33.5 MB bf16
    unsigned short* VT = KR + (size_t)BH * NTOK * DDIM;               // 33.5 MB bf16
    float* O = (float*)d_out;

    rope_k<<<(BH * NTOK * DDIM / 8) / 256, 256, 0, stream>>>(K, KR);
    transpose_v<<<BH * (NTOK / 64), 256, 0, stream>>>(V, VT);
    flash_attn<<<BH * (NTOK / QT), 256, 0, stream>>>(Q, KR, VT, O);
}